// Round 1
// baseline (349.195 us; speedup 1.0000x reference)
//
#include <hip/hip_runtime.h>

// GIN 2-layer, N=100000, E=1600000, D=128.
// R6: aggregate restructured for latency. Per-node adjacency segment is
// contiguous in srt -> one coalesced 64-lane preload replaces per-trip srt
// loads; row index per trip comes from ds_bpermute (shfl). Gather loop
// unrolled 4 (all gathers independent). Layer1 uses SORT=1 (in-register
// 64-lane bitonic sort of edge ids -> quantile-lockstep gather stream for
// L2 locality A/B), layer2 SORT=0. Rare deg>64 tail loop kept for
// correctness on arbitrary graphs.

typedef __attribute__((ext_vector_type(8))) short bf16x8;
typedef __attribute__((ext_vector_type(4))) float floatx4;

#define WS_ALIGN(x) (((x) + 255) & ~(size_t)255)
#define NBMAX 400   // max buckets (n <= 102400)
#define BCAP 6144   // per-bucket capacity (mean 4096, sd ~64)

__device__ __forceinline__ unsigned short f2b(float f) {  // RTNE fp32->bf16
  unsigned u = __builtin_bit_cast(unsigned, f);
  u = (u + 0x7FFF + ((u >> 16) & 1)) >> 16;
  return (unsigned short)u;
}
__device__ __forceinline__ float b2f(unsigned u16) {  // low 16 bits = bf16
  return __builtin_bit_cast(float, u16 << 16);
}

// ---------- phase A: multisplit edges into 256-node buckets ----------
__global__ __launch_bounds__(256) void bucket_split(const int* __restrict__ src,
                                                    const int* __restrict__ dst,
                                                    int* __restrict__ bcnt,
                                                    unsigned* __restrict__ barr, int E, int nb) {
  __shared__ int cnt[NBMAX], base[NBMAX], cur[NBMAX];
  int t = threadIdx.x;
  for (int i = t; i < nb; i += 256) { cnt[i] = 0; cur[i] = 0; }
  __syncthreads();
  int e0 = blockIdx.x * 8192;
  int s[32], d[32];
#pragma unroll
  for (int k = 0; k < 32; k++) {
    int e = e0 + k * 256 + t;
    if (e < E) { s[k] = src[e]; d[k] = dst[e]; } else { d[k] = -1; }
  }
#pragma unroll
  for (int k = 0; k < 32; k++)
    if (d[k] >= 0) atomicAdd(&cnt[d[k] >> 8], 1);
  __syncthreads();
  for (int i = t; i < nb; i += 256) base[i] = cnt[i] ? atomicAdd(&bcnt[i], cnt[i]) : 0;
  __syncthreads();
#pragma unroll
  for (int k = 0; k < 32; k++)
    if (d[k] >= 0) {
      int b = d[k] >> 8;
      int r = atomicAdd(&cur[b], 1);
      barr[(size_t)b * BCAP + base[b] + r] = ((unsigned)(d[k] & 255) << 17) | (unsigned)s[k];
    }
}

// ---------- phase B: scan bucket counts ----------
__global__ void bucket_scan(const int* __restrict__ bcnt, int* __restrict__ sbase, int nb,
                            int* __restrict__ rowptr, int n) {
  __shared__ int buf[512];
  int t = threadIdx.x;
  int v = (t < nb) ? bcnt[t] : 0;
  buf[t] = v;
  __syncthreads();
  for (int off = 1; off < 512; off <<= 1) {
    int add = (t >= off) ? buf[t - off] : 0;
    __syncthreads();
    buf[t] += add;
    __syncthreads();
  }
  if (t < nb) sbase[t] = buf[t] - v;  // exclusive
  if (t == nb - 1) { sbase[nb] = buf[t]; rowptr[n] = buf[t]; }
}

// ---------- phase C: per-bucket CSR finalize ----------
__global__ __launch_bounds__(256) void bucket_csr(const unsigned* __restrict__ barr,
                                                  const int* __restrict__ bcnt,
                                                  const int* __restrict__ sbase,
                                                  int* __restrict__ rowptr, int* __restrict__ srt,
                                                  int n) {
  __shared__ int cnt[256], off[256], off2[256];
  int b = blockIdx.x, t = threadIdx.x;
  int cb = bcnt[b];
  int node0 = b * 256;
  int nlocal = min(256, n - node0);
  cnt[t] = 0;
  off2[t] = 0;
  __syncthreads();
  const unsigned* bp = barr + (size_t)b * BCAP;
  for (int i = t; i < cb; i += 256) atomicAdd(&cnt[bp[i] >> 17], 1);
  __syncthreads();
  int v = cnt[t];
  off[t] = v;
  __syncthreads();
  for (int o = 1; o < 256; o <<= 1) {
    int add = (t >= o) ? off[t - o] : 0;
    __syncthreads();
    off[t] += add;
    __syncthreads();
  }
  int excl = off[t] - v;
  int sb = sbase[b];
  if (t < nlocal) rowptr[node0 + t] = sb + excl;
  cnt[t] = excl;
  __syncthreads();
  for (int i = t; i < cb; i += 256) {
    unsigned pk = bp[i];
    int local = pk >> 17;
    int r = atomicAdd(&off2[local], 1);
    srt[sb + cnt[local] + r] = pk & 0x1FFFF;
  }
}

// ---------- fp32 -> bf16 convert (row-major) ----------
__global__ void cvt_kernel(const float* __restrict__ x, unsigned short* __restrict__ xb, int n4) {
  int i = blockIdx.x * blockDim.x + threadIdx.x;
  if (i < n4) {
    float4 v = ((const float4*)x)[i];
    uint2 pk;
    pk.x = (unsigned)f2b(v.x) | ((unsigned)f2b(v.y) << 16);
    pk.y = (unsigned)f2b(v.z) | ((unsigned)f2b(v.w) << 16);
    ((uint2*)xb)[i] = pk;
  }
}

__device__ __forceinline__ void acc8(float* acc, uint4 u) {
  acc[0] += __builtin_bit_cast(float, u.x << 16);
  acc[1] += __builtin_bit_cast(float, u.x & 0xffff0000u);
  acc[2] += __builtin_bit_cast(float, u.y << 16);
  acc[3] += __builtin_bit_cast(float, u.y & 0xffff0000u);
  acc[4] += __builtin_bit_cast(float, u.z << 16);
  acc[5] += __builtin_bit_cast(float, u.z & 0xffff0000u);
  acc[6] += __builtin_bit_cast(float, u.w << 16);
  acc[7] += __builtin_bit_cast(float, u.w & 0xffff0000u);
}

// ---------- aggregation (bf16 in/out, fp32 accumulate) ----------
// one wave per node. lane = (s<<4)|c: s = edge slot (0..3), c = 16B chunk.
// Adjacency segment [p0,e) is contiguous -> ONE coalesced 64-lane preload
// of edge ids; per-trip row id is a ds_bpermute broadcast (no VMEM load on
// the critical path). All gathers independent -> unroll 4 fills the
// latency window. SORT=1: in-register bitonic sort of the 64 ids so
// co-resident waves sweep ascending ids in quantile lockstep (L2 band).
template <int SORT>
__global__ __launch_bounds__(256) void aggregate_bf16(const unsigned short* __restrict__ X,
                                                      const int* __restrict__ rowptr,
                                                      const int* __restrict__ srt,
                                                      unsigned short* __restrict__ out, int n) {
  int w = blockIdx.x * 4 + (threadIdx.x >> 6);
  if (w >= n) return;
  int lane = threadIdx.x & 63;
  int c = lane & 15;  // 16B chunk within row
  int s = lane >> 4;  // edge slot
  const uint4* Xv = (const uint4*)X;  // 16 uint4 per row

  int p0 = rowptr[w], e = rowptr[w + 1];
  int deg = e - p0;

  // coalesced preload of up to 64 edge ids (deg > 64 -> tail loop)
  int pre = 0x7fffffff;
  if (lane < deg) pre = srt[p0 + lane];

  if (SORT) {
    // 64-lane bitonic sort, ascending; INT_MAX pads sort to the top
#pragma unroll
    for (int k = 2; k <= 64; k <<= 1) {
#pragma unroll
      for (int j = k >> 1; j >= 1; j >>= 1) {
        int p = __shfl_xor(pre, j, 64);
        bool keepmin = ((lane & k) == 0) == ((lane & j) == 0);
        pre = keepmin ? min(pre, p) : max(pre, p);
      }
    }
  }

  float acc[8];
#pragma unroll
  for (int i = 0; i < 8; i++) acc[i] = 0.f;

  // self row: slot 0 only
  if (s == 0) {
    uint4 u = Xv[(size_t)w * 16 + c];
    acc8(acc, u);
  }

  int trips = (deg + 3) >> 2;
  int tpre = trips < 16 ? trips : 16;
#pragma unroll 4
  for (int i = 0; i < tpre; i++) {
    int j = 4 * i + s;
    int r = __shfl(pre, j < deg ? j : 0, 64);
    uint4 u = Xv[(size_t)r * 16 + c];
    if (j >= deg) { u.x = 0; u.y = 0; u.z = 0; u.w = 0; }
    acc8(acc, u);
  }
  // tail for deg > 64 (never taken for Poisson(16) data; correctness only)
  for (int idx = p0 + 64 + s; idx < e; idx += 4) {
    int r = srt[idx];
    uint4 u = Xv[(size_t)r * 16 + c];
    acc8(acc, u);
  }

  // reduce across slots (lane bits 4,5)
#pragma unroll
  for (int i = 0; i < 8; i++) {
    acc[i] += __shfl_xor(acc[i], 16, 64);
    acc[i] += __shfl_xor(acc[i], 32, 64);
  }

  // lane (c,s) writes uint c*4+s = cols (c*8+2s, c*8+2s+1)
  unsigned pk = (unsigned)f2b(acc[2 * s]) | ((unsigned)f2b(acc[2 * s + 1]) << 16);
  ((unsigned*)out)[(size_t)w * 64 + c * 4 + s] = pk;
}

// ---------- fused MLP: C = (relu(A@Wa^T+ba)) @ Wb^T + bb ----------
__device__ __forceinline__ void stage_w(char* buf, const float* __restrict__ W, int t) {
  for (int idx = t; idx < 2048; idx += 512) {  // idx = 16B-chunk id (8 bf16)
    int nrow = idx >> 4, c = idx & 15;
    float4 a = ((const float4*)W)[idx * 2];
    float4 b = ((const float4*)W)[idx * 2 + 1];
    uint4 pk;
    pk.x = (unsigned)f2b(a.x) | ((unsigned)f2b(a.y) << 16);
    pk.y = (unsigned)f2b(a.z) | ((unsigned)f2b(a.w) << 16);
    pk.z = (unsigned)f2b(b.x) | ((unsigned)f2b(b.y) << 16);
    pk.w = (unsigned)f2b(b.z) | ((unsigned)f2b(b.w) << 16);
    *(uint4*)(buf + nrow * 256 + ((c ^ (nrow & 15)) << 4)) = pk;
  }
}

template <int OUT_BF16>
__global__ __launch_bounds__(512) void mlp_kernel(
    const unsigned short* __restrict__ A, const float* __restrict__ Wa,
    const float* __restrict__ ba, const float* __restrict__ Wb,
    const float* __restrict__ bb, void* __restrict__ Cout, int n) {
  __shared__ __align__(16) char lds[65536];
  char* bufA = lds;          // Wa, later h
  char* bufB = lds + 32768;  // Wb
  int t = threadIdx.x;
  stage_w(bufA, Wa, t);
  stage_w(bufB, Wb, t);

  int wave = t >> 6, lane = t & 63;
  int m = lane & 15, q = lane >> 4;
  int rbase = blockIdx.x * 128;
  int rowA = rbase + wave * 16 + m;
  int rA = rowA < n ? rowA : (n - 1);

  bf16x8 af[4];
  const bf16x8* Arow = (const bf16x8*)(A + (size_t)rA * 128);
#pragma unroll
  for (int ks = 0; ks < 4; ks++) af[ks] = Arow[ks * 4 + q];

  __syncthreads();

  floatx4 acc[8];
  floatx4 zf = {0.f, 0.f, 0.f, 0.f};
#pragma unroll
  for (int j = 0; j < 8; j++) acc[j] = zf;
#pragma unroll
  for (int ks = 0; ks < 4; ks++) {
#pragma unroll
    for (int j = 0; j < 8; j++) {
      bf16x8 bf = *(const bf16x8*)(bufA + (j * 16 + m) * 256 + (((ks * 4 + q) ^ m) << 4));
      acc[j] = __builtin_amdgcn_mfma_f32_16x16x32_bf16(af[ks], bf, acc[j], 0, 0, 0);
    }
  }
  __syncthreads();

#pragma unroll
  for (int j = 0; j < 8; j++) {
    float bias = ba[j * 16 + m];
#pragma unroll
    for (int reg = 0; reg < 4; reg++) {
      float v = fmaxf(acc[j][reg] + bias, 0.f);
      int lr = wave * 16 + q * 4 + reg;
      int col = j * 16 + m;
      *(unsigned short*)(bufA + lr * 256 + (((col >> 3) ^ (lr & 15)) << 4) + (col & 7) * 2) =
          f2b(v);
    }
  }
  __syncthreads();

  int lrA = wave * 16 + m;
#pragma unroll
  for (int ks = 0; ks < 4; ks++)
    af[ks] = *(const bf16x8*)(bufA + lrA * 256 + (((ks * 4 + q) ^ m) << 4));
#pragma unroll
  for (int j = 0; j < 8; j++) acc[j] = zf;
#pragma unroll
  for (int ks = 0; ks < 4; ks++) {
#pragma unroll
    for (int j = 0; j < 8; j++) {
      bf16x8 bf = *(const bf16x8*)(bufB + (j * 16 + m) * 256 + (((ks * 4 + q) ^ m) << 4));
      acc[j] = __builtin_amdgcn_mfma_f32_16x16x32_bf16(af[ks], bf, acc[j], 0, 0, 0);
    }
  }

#pragma unroll
  for (int j = 0; j < 8; j++) {
    float bias = bb[j * 16 + m];
#pragma unroll
    for (int reg = 0; reg < 4; reg++) {
      int row = rbase + wave * 16 + q * 4 + reg;
      if (row >= n) continue;
      float v = acc[j][reg] + bias;
      int col = j * 16 + m;
      if (OUT_BF16)
        ((unsigned short*)Cout)[(size_t)row * 128 + col] = f2b(v);
      else
        ((float*)Cout)[(size_t)row * 128 + col] = v;
    }
  }
}

extern "C" void kernel_launch(void* const* d_in, const int* in_sizes, int n_in,
                              void* d_out, int out_size, void* d_ws, size_t ws_size,
                              hipStream_t stream) {
  const float* x   = (const float*)d_in[0];
  const int*   ei  = (const int*)d_in[1];
  const float* w0a = (const float*)d_in[2];
  const float* b0a = (const float*)d_in[3];
  const float* w0b = (const float*)d_in[4];
  const float* b0b = (const float*)d_in[5];
  const float* w1a = (const float*)d_in[6];
  const float* b1a = (const float*)d_in[7];
  const float* w1b = (const float*)d_in[8];
  const float* b1b = (const float*)d_in[9];
  float* out = (float*)d_out;

  int n = in_sizes[0] / 128;  // 100000
  int E = in_sizes[1] / 2;    // 1600000
  const int* src = ei;
  const int* dst = ei + E;
  int nb = (n + 255) / 256;  // 391

  char* w = (char*)d_ws;
  int* rowptr = (int*)w;           w += WS_ALIGN((size_t)(n + 1) * 4);
  int* sbase = (int*)w;            w += WS_ALIGN((size_t)(NBMAX + 1) * 4);
  int* bcnt = (int*)w;             w += WS_ALIGN((size_t)NBMAX * 4);
  int* srt = (int*)w;              w += WS_ALIGN((size_t)E * 4);
  unsigned short* xb = (unsigned short*)w;  w += WS_ALIGN((size_t)n * 128 * 2);
  // barr (nb*BCAP uints, ~9.6MB) overlaps B1: barr is dead before the first
  // aggregate writes B1.
  unsigned* barr = (unsigned*)w;
  unsigned short* B1 = (unsigned short*)w;

  // ---- CSR build (hierarchical) ----
  hipMemsetAsync(bcnt, 0, (size_t)nb * 4, stream);
  bucket_split<<<(E + 8191) / 8192, 256, 0, stream>>>(src, dst, bcnt, barr, E, nb);
  bucket_scan<<<1, 512, 0, stream>>>(bcnt, sbase, nb, rowptr, n);
  bucket_csr<<<nb, 256, 0, stream>>>(barr, bcnt, sbase, rowptr, srt, n);

  // ---- x -> bf16 ----
  cvt_kernel<<<(n * 32 + 255) / 256, 256, 0, stream>>>(x, xb, n * 32);

  int agg_grid = (n + 3) / 4;
  int mlp_grid = (n + 127) / 128;

  // ---- layer 1 ----  (xb -> B1 -> xb)   SORT=1 (A/B: sorted gather stream)
  aggregate_bf16<1><<<agg_grid, 256, 0, stream>>>(xb, rowptr, srt, B1, n);
  mlp_kernel<1><<<mlp_grid, 512, 0, stream>>>(B1, w0a, b0a, w0b, b0b, xb, n);

  // ---- layer 2 ----  (xb -> B1 -> out)  SORT=0 (A/B control)
  aggregate_bf16<0><<<agg_grid, 256, 0, stream>>>(xb, rowptr, srt, B1, n);
  mlp_kernel<0><<<mlp_grid, 512, 0, stream>>>(B1, w1a, b1a, w1b, b1b, out, n);
}

// Round 2
// 331.384 us; speedup vs baseline: 1.0537x; 1.0537x over previous
//
#include <hip/hip_runtime.h>

// GIN 2-layer, N=100000, E=1600000, D=128.
// R7: revert R6's preload+shfl (LDS-pipe serialization, -13us). Aggregate
// now processes edge slots in GROUPS of 4 trips: 4 srt broadcast loads
// issued as one vmcnt batch, then 4 independent 1KB gathers, then
// accumulate -> one latency round trip per 16 edges instead of one per 2
// trips (R5 unroll-2). Self-row load hoisted ahead of the loop. float2
// accumulators to allow v_pk_add_f32 packing.

typedef __attribute__((ext_vector_type(8))) short bf16x8;
typedef __attribute__((ext_vector_type(4))) float floatx4;
typedef __attribute__((ext_vector_type(2))) float floatx2;

#define WS_ALIGN(x) (((x) + 255) & ~(size_t)255)
#define NBMAX 400   // max buckets (n <= 102400)
#define BCAP 6144   // per-bucket capacity (mean 4096, sd ~64)

__device__ __forceinline__ unsigned short f2b(float f) {  // RTNE fp32->bf16
  unsigned u = __builtin_bit_cast(unsigned, f);
  u = (u + 0x7FFF + ((u >> 16) & 1)) >> 16;
  return (unsigned short)u;
}

// unpack a dword of 2 bf16 into {lo,hi} as f32 pair
__device__ __forceinline__ floatx2 bpair(unsigned d) {
  floatx2 r;
  r[0] = __builtin_bit_cast(float, d << 16);
  r[1] = __builtin_bit_cast(float, d & 0xffff0000u);
  return r;
}

// ---------- phase A: multisplit edges into 256-node buckets ----------
__global__ __launch_bounds__(256) void bucket_split(const int* __restrict__ src,
                                                    const int* __restrict__ dst,
                                                    int* __restrict__ bcnt,
                                                    unsigned* __restrict__ barr, int E, int nb) {
  __shared__ int cnt[NBMAX], base[NBMAX], cur[NBMAX];
  int t = threadIdx.x;
  for (int i = t; i < nb; i += 256) { cnt[i] = 0; cur[i] = 0; }
  __syncthreads();
  int e0 = blockIdx.x * 8192;
  int s[32], d[32];
#pragma unroll
  for (int k = 0; k < 32; k++) {
    int e = e0 + k * 256 + t;
    if (e < E) { s[k] = src[e]; d[k] = dst[e]; } else { d[k] = -1; }
  }
#pragma unroll
  for (int k = 0; k < 32; k++)
    if (d[k] >= 0) atomicAdd(&cnt[d[k] >> 8], 1);
  __syncthreads();
  for (int i = t; i < nb; i += 256) base[i] = cnt[i] ? atomicAdd(&bcnt[i], cnt[i]) : 0;
  __syncthreads();
#pragma unroll
  for (int k = 0; k < 32; k++)
    if (d[k] >= 0) {
      int b = d[k] >> 8;
      int r = atomicAdd(&cur[b], 1);
      barr[(size_t)b * BCAP + base[b] + r] = ((unsigned)(d[k] & 255) << 17) | (unsigned)s[k];
    }
}

// ---------- phase B: scan bucket counts ----------
__global__ void bucket_scan(const int* __restrict__ bcnt, int* __restrict__ sbase, int nb,
                            int* __restrict__ rowptr, int n) {
  __shared__ int buf[512];
  int t = threadIdx.x;
  int v = (t < nb) ? bcnt[t] : 0;
  buf[t] = v;
  __syncthreads();
  for (int off = 1; off < 512; off <<= 1) {
    int add = (t >= off) ? buf[t - off] : 0;
    __syncthreads();
    buf[t] += add;
    __syncthreads();
  }
  if (t < nb) sbase[t] = buf[t] - v;  // exclusive
  if (t == nb - 1) { sbase[nb] = buf[t]; rowptr[n] = buf[t]; }
}

// ---------- phase C: per-bucket CSR finalize ----------
__global__ __launch_bounds__(256) void bucket_csr(const unsigned* __restrict__ barr,
                                                  const int* __restrict__ bcnt,
                                                  const int* __restrict__ sbase,
                                                  int* __restrict__ rowptr, int* __restrict__ srt,
                                                  int n) {
  __shared__ int cnt[256], off[256], off2[256];
  int b = blockIdx.x, t = threadIdx.x;
  int cb = bcnt[b];
  int node0 = b * 256;
  int nlocal = min(256, n - node0);
  cnt[t] = 0;
  off2[t] = 0;
  __syncthreads();
  const unsigned* bp = barr + (size_t)b * BCAP;
  for (int i = t; i < cb; i += 256) atomicAdd(&cnt[bp[i] >> 17], 1);
  __syncthreads();
  int v = cnt[t];
  off[t] = v;
  __syncthreads();
  for (int o = 1; o < 256; o <<= 1) {
    int add = (t >= o) ? off[t - o] : 0;
    __syncthreads();
    off[t] += add;
    __syncthreads();
  }
  int excl = off[t] - v;
  int sb = sbase[b];
  if (t < nlocal) rowptr[node0 + t] = sb + excl;
  cnt[t] = excl;
  __syncthreads();
  for (int i = t; i < cb; i += 256) {
    unsigned pk = bp[i];
    int local = pk >> 17;
    int r = atomicAdd(&off2[local], 1);
    srt[sb + cnt[local] + r] = pk & 0x1FFFF;
  }
}

// ---------- fp32 -> bf16 convert (row-major) ----------
__global__ void cvt_kernel(const float* __restrict__ x, unsigned short* __restrict__ xb, int n4) {
  int i = blockIdx.x * blockDim.x + threadIdx.x;
  if (i < n4) {
    float4 v = ((const float4*)x)[i];
    uint2 pk;
    pk.x = (unsigned)f2b(v.x) | ((unsigned)f2b(v.y) << 16);
    pk.y = (unsigned)f2b(v.z) | ((unsigned)f2b(v.w) << 16);
    ((uint2*)xb)[i] = pk;
  }
}

// ---------- aggregation (bf16 in/out, fp32 accumulate) ----------
// one wave per node. lane = (s<<4)|c: s = edge slot (0..3), c = 16B chunk
// (0..15). Trips processed in groups of 4: 4 srt broadcast loads issued
// back-to-back (one vmcnt batch), then 4 independent 1KB gathers, then
// accumulate. One latency round trip covers 16 edges (mean degree 16).
__global__ __launch_bounds__(256) void aggregate_bf16(const unsigned short* __restrict__ X,
                                                      const int* __restrict__ rowptr,
                                                      const int* __restrict__ srt,
                                                      unsigned short* __restrict__ out, int n) {
  int w = blockIdx.x * 4 + (threadIdx.x >> 6);
  if (w >= n) return;
  int lane = threadIdx.x & 63;
  int c = lane & 15;  // 16B chunk within row
  int s = lane >> 4;  // edge slot
  const uint4* Xv = (const uint4*)X;  // 16 uint4 per row

  int p0 = rowptr[w], e = rowptr[w + 1];
  int deg = e - p0;
  int trips = (deg + 3) >> 2;

  // self row: issue early (slot 0 lanes only); accumulated after the loop
  uint4 uself = {0, 0, 0, 0};
  if (s == 0) uself = Xv[(size_t)w * 16 + c];

  floatx2 acc2[4];
#pragma unroll
  for (int i = 0; i < 4; i++) acc2[i] = floatx2{0.f, 0.f};

  for (int g = 0; g < trips; g += 4) {
    int idx[4];
    bool val[4];
#pragma unroll
    for (int k = 0; k < 4; k++) {
      int j = (g + k) * 4 + s;
      val[k] = j < deg;
      idx[k] = srt[p0 + (val[k] ? j : 0)];
    }
    uint4 u[4];
#pragma unroll
    for (int k = 0; k < 4; k++) u[k] = Xv[(size_t)idx[k] * 16 + c];
#pragma unroll
    for (int k = 0; k < 4; k++) {
      if (!val[k]) { u[k].x = 0; u[k].y = 0; u[k].z = 0; u[k].w = 0; }
      acc2[0] += bpair(u[k].x);
      acc2[1] += bpair(u[k].y);
      acc2[2] += bpair(u[k].z);
      acc2[3] += bpair(u[k].w);
    }
  }

  // fold in self row (zeros for s != 0 lanes)
  acc2[0] += bpair(uself.x);
  acc2[1] += bpair(uself.y);
  acc2[2] += bpair(uself.z);
  acc2[3] += bpair(uself.w);

  // reduce across slots (lane bits 4,5)
#pragma unroll
  for (int i = 0; i < 4; i++) {
#pragma unroll
    for (int h = 0; h < 2; h++) {
      acc2[i][h] += __shfl_xor(acc2[i][h], 16, 64);
      acc2[i][h] += __shfl_xor(acc2[i][h], 32, 64);
    }
  }

  // lane (c,s) writes dword c*4+s = cols (c*8+2s, c*8+2s+1) = acc2[s]
  unsigned pk = (unsigned)f2b(acc2[s][0]) | ((unsigned)f2b(acc2[s][1]) << 16);
  ((unsigned*)out)[(size_t)w * 64 + c * 4 + s] = pk;
}

// ---------- fused MLP: C = (relu(A@Wa^T+ba)) @ Wb^T + bb ----------
__device__ __forceinline__ void stage_w(char* buf, const float* __restrict__ W, int t) {
  for (int idx = t; idx < 2048; idx += 512) {  // idx = 16B-chunk id (8 bf16)
    int nrow = idx >> 4, c = idx & 15;
    float4 a = ((const float4*)W)[idx * 2];
    float4 b = ((const float4*)W)[idx * 2 + 1];
    uint4 pk;
    pk.x = (unsigned)f2b(a.x) | ((unsigned)f2b(a.y) << 16);
    pk.y = (unsigned)f2b(a.z) | ((unsigned)f2b(a.w) << 16);
    pk.z = (unsigned)f2b(b.x) | ((unsigned)f2b(b.y) << 16);
    pk.w = (unsigned)f2b(b.z) | ((unsigned)f2b(b.w) << 16);
    *(uint4*)(buf + nrow * 256 + ((c ^ (nrow & 15)) << 4)) = pk;
  }
}

template <int OUT_BF16>
__global__ __launch_bounds__(512) void mlp_kernel(
    const unsigned short* __restrict__ A, const float* __restrict__ Wa,
    const float* __restrict__ ba, const float* __restrict__ Wb,
    const float* __restrict__ bb, void* __restrict__ Cout, int n) {
  __shared__ __align__(16) char lds[65536];
  char* bufA = lds;          // Wa, later h
  char* bufB = lds + 32768;  // Wb
  int t = threadIdx.x;
  stage_w(bufA, Wa, t);
  stage_w(bufB, Wb, t);

  int wave = t >> 6, lane = t & 63;
  int m = lane & 15, q = lane >> 4;
  int rbase = blockIdx.x * 128;
  int rowA = rbase + wave * 16 + m;
  int rA = rowA < n ? rowA : (n - 1);

  bf16x8 af[4];
  const bf16x8* Arow = (const bf16x8*)(A + (size_t)rA * 128);
#pragma unroll
  for (int ks = 0; ks < 4; ks++) af[ks] = Arow[ks * 4 + q];

  __syncthreads();

  floatx4 acc[8];
  floatx4 zf = {0.f, 0.f, 0.f, 0.f};
#pragma unroll
  for (int j = 0; j < 8; j++) acc[j] = zf;
#pragma unroll
  for (int ks = 0; ks < 4; ks++) {
#pragma unroll
    for (int j = 0; j < 8; j++) {
      bf16x8 bf = *(const bf16x8*)(bufA + (j * 16 + m) * 256 + (((ks * 4 + q) ^ m) << 4));
      acc[j] = __builtin_amdgcn_mfma_f32_16x16x32_bf16(af[ks], bf, acc[j], 0, 0, 0);
    }
  }
  __syncthreads();

#pragma unroll
  for (int j = 0; j < 8; j++) {
    float bias = ba[j * 16 + m];
#pragma unroll
    for (int reg = 0; reg < 4; reg++) {
      float v = fmaxf(acc[j][reg] + bias, 0.f);
      int lr = wave * 16 + q * 4 + reg;
      int col = j * 16 + m;
      *(unsigned short*)(bufA + lr * 256 + (((col >> 3) ^ (lr & 15)) << 4) + (col & 7) * 2) =
          f2b(v);
    }
  }
  __syncthreads();

  int lrA = wave * 16 + m;
#pragma unroll
  for (int ks = 0; ks < 4; ks++)
    af[ks] = *(const bf16x8*)(bufA + lrA * 256 + (((ks * 4 + q) ^ m) << 4));
#pragma unroll
  for (int j = 0; j < 8; j++) acc[j] = zf;
#pragma unroll
  for (int ks = 0; ks < 4; ks++) {
#pragma unroll
    for (int j = 0; j < 8; j++) {
      bf16x8 bf = *(const bf16x8*)(bufB + (j * 16 + m) * 256 + (((ks * 4 + q) ^ m) << 4));
      acc[j] = __builtin_amdgcn_mfma_f32_16x16x32_bf16(af[ks], bf, acc[j], 0, 0, 0);
    }
  }

#pragma unroll
  for (int j = 0; j < 8; j++) {
    float bias = bb[j * 16 + m];
#pragma unroll
    for (int reg = 0; reg < 4; reg++) {
      int row = rbase + wave * 16 + q * 4 + reg;
      if (row >= n) continue;
      float v = acc[j][reg] + bias;
      int col = j * 16 + m;
      if (OUT_BF16)
        ((unsigned short*)Cout)[(size_t)row * 128 + col] = f2b(v);
      else
        ((float*)Cout)[(size_t)row * 128 + col] = v;
    }
  }
}

extern "C" void kernel_launch(void* const* d_in, const int* in_sizes, int n_in,
                              void* d_out, int out_size, void* d_ws, size_t ws_size,
                              hipStream_t stream) {
  const float* x   = (const float*)d_in[0];
  const int*   ei  = (const int*)d_in[1];
  const float* w0a = (const float*)d_in[2];
  const float* b0a = (const float*)d_in[3];
  const float* w0b = (const float*)d_in[4];
  const float* b0b = (const float*)d_in[5];
  const float* w1a = (const float*)d_in[6];
  const float* b1a = (const float*)d_in[7];
  const float* w1b = (const float*)d_in[8];
  const float* b1b = (const float*)d_in[9];
  float* out = (float*)d_out;

  int n = in_sizes[0] / 128;  // 100000
  int E = in_sizes[1] / 2;    // 1600000
  const int* src = ei;
  const int* dst = ei + E;
  int nb = (n + 255) / 256;  // 391

  char* w = (char*)d_ws;
  int* rowptr = (int*)w;           w += WS_ALIGN((size_t)(n + 1) * 4);
  int* sbase = (int*)w;            w += WS_ALIGN((size_t)(NBMAX + 1) * 4);
  int* bcnt = (int*)w;             w += WS_ALIGN((size_t)NBMAX * 4);
  int* srt = (int*)w;              w += WS_ALIGN((size_t)E * 4);
  unsigned short* xb = (unsigned short*)w;  w += WS_ALIGN((size_t)n * 128 * 2);
  // barr (nb*BCAP uints, ~9.6MB) overlaps B1: barr is dead before the first
  // aggregate writes B1.
  unsigned* barr = (unsigned*)w;
  unsigned short* B1 = (unsigned short*)w;

  // ---- CSR build (hierarchical) ----
  hipMemsetAsync(bcnt, 0, (size_t)nb * 4, stream);
  bucket_split<<<(E + 8191) / 8192, 256, 0, stream>>>(src, dst, bcnt, barr, E, nb);
  bucket_scan<<<1, 512, 0, stream>>>(bcnt, sbase, nb, rowptr, n);
  bucket_csr<<<nb, 256, 0, stream>>>(barr, bcnt, sbase, rowptr, srt, n);

  // ---- x -> bf16 ----
  cvt_kernel<<<(n * 32 + 255) / 256, 256, 0, stream>>>(x, xb, n * 32);

  int agg_grid = (n + 3) / 4;
  int mlp_grid = (n + 127) / 128;

  // ---- layer 1 ----  (xb -> B1 -> xb)
  aggregate_bf16<<<agg_grid, 256, 0, stream>>>(xb, rowptr, srt, B1, n);
  mlp_kernel<1><<<mlp_grid, 512, 0, stream>>>(B1, w0a, b0a, w0b, b0b, xb, n);

  // ---- layer 2 ----  (xb -> B1 -> out)
  aggregate_bf16<<<agg_grid, 256, 0, stream>>>(xb, rowptr, srt, B1, n);
  mlp_kernel<0><<<mlp_grid, 512, 0, stream>>>(B1, w1a, b1a, w1b, b1b, out, n);
}